// Round 4
// baseline (47.752 us; speedup 1.0000x reference)
//
#include <hip/hip_runtime.h>

#define NN 4096
#define EE 65536
#define DD 128

// ---------------- zero degree arrays ----------------
__global__ void k_zero(int* __restrict__ p) {
    p[blockIdx.x * 256 + threadIdx.x] = 0;   // 32 x 256 = 8192 ints
}

// ---------------- degree count: 2 edges/thread via int2 ----------------
__global__ void k_deg(const int* __restrict__ ei, int* __restrict__ indeg,
                      int* __restrict__ outdeg) {
    int t = blockIdx.x * 512 + threadIdx.x;
    int2 s = *(const int2*)&ei[2 * t];
    int2 d = *(const int2*)&ei[EE + 2 * t];
    atomicAdd(&outdeg[s.x], 1);
    atomicAdd(&outdeg[s.y], 1);
    atomicAdd(&indeg[d.x], 1);
    atomicAdd(&indeg[d.y], 1);
}

// same-wave LDS write->read ordering (no cross-wave sharing anywhere)
__device__ __forceinline__ void lds_fence() {
    asm volatile("s_waitcnt lgkmcnt(0)" ::: "memory");
}

__device__ __forceinline__ float wsum(float v) {
    v += __shfl_xor(v, 32); v += __shfl_xor(v, 16); v += __shfl_xor(v, 8);
    v += __shfl_xor(v, 4);  v += __shfl_xor(v, 2);  v += __shfl_xor(v, 1);
    return v;
}

// acc += y @ W for 2 nodes; W float2 per lane feeds 4 FMAs (2x reuse)
__device__ __forceinline__ void gemm2(const float* __restrict__ W,
                                      const float* __restrict__ y0,
                                      const float* __restrict__ y1,
                                      int K4, int d2, float2& a0, float2& a1) {
#pragma unroll 4
    for (int k4 = 0; k4 < K4; ++k4) {
        float4 v0 = *(const float4*)&y0[k4 * 4];   // LDS broadcast
        float4 v1 = *(const float4*)&y1[k4 * 4];
#pragma unroll
        for (int kk = 0; kk < 4; ++kk) {
            float2 w = *(const float2*)&W[(k4 * 4 + kk) * DD + d2];  // L1/L2
            float e0 = kk == 0 ? v0.x : kk == 1 ? v0.y : kk == 2 ? v0.z : v0.w;
            float e1 = kk == 0 ? v1.x : kk == 1 ? v1.y : kk == 2 ? v1.z : v1.w;
            a0.x += e0 * w.x; a0.y += e0 * w.y;
            a1.x += e1 * w.x; a1.y += e1 * w.y;
        }
    }
}

// ---------------- fused pipeline: wave = 2 nodes, zero barriers --------------
// Attention output is exactly zero (multiplicative -1e6 mask => softmax max is a
// huge positive cross-graph logit => within-graph exp underflows to 0; the zero
// mask then kills the cross-graph cols) -- only xp=h+bo and the LN2/FF path survive.
__global__ __launch_bounds__(256) void k_pipe(
    const float* __restrict__ x, const float* __restrict__ W_in,
    const float* __restrict__ b_in, const float* __restrict__ z_in,
    const float* __restrict__ z_out, const int* __restrict__ indeg,
    const int* __restrict__ outdeg, const float* __restrict__ bo_all,
    const float* __restrict__ g_all, const float* __restrict__ b_all,
    const float* __restrict__ Wff_all, const float* __restrict__ bff_all,
    const float* __restrict__ W_out, const float* __restrict__ b_out,
    float* __restrict__ out) {
    __shared__ float ybuf[4][2][DD];   // 4 KB; strictly same-wave use
    const int tid = threadIdx.x, lane = tid & 63, wv = tid >> 6;
    const int n0 = (blockIdx.x * 4 + wv) * 2;
    const int d2 = lane * 2;
    float* y0 = &ybuf[wv][0][0];
    float* y1 = &ybuf[wv][1][0];

    // stage x rows (64 floats each) + independent lookups
    y0[lane] = x[(size_t)n0 * 64 + lane];
    y1[lane] = x[(size_t)(n0 + 1) * 64 + lane];
    int di0 = min(indeg[n0], 63), dq0 = min(outdeg[n0], 63);
    int di1 = min(indeg[n0 + 1], 63), dq1 = min(outdeg[n0 + 1], 63);
    float2 bi = *(const float2*)&b_in[d2];
    float2 zi0 = *(const float2*)&z_in[(size_t)di0 * DD + d2];
    float2 zo0 = *(const float2*)&z_out[(size_t)dq0 * DD + d2];
    float2 zi1 = *(const float2*)&z_in[(size_t)di1 * DD + d2];
    float2 zo1 = *(const float2*)&z_out[(size_t)dq1 * DD + d2];

    lds_fence();
    float2 a0 = {0.f, 0.f}, a1 = {0.f, 0.f};
    gemm2(W_in, y0, y1, 16, d2, a0, a1);            // h0 GEMM, K=64
    float2 h0 = {a0.x + bi.x + zi0.x + zo0.x, a0.y + bi.y + zi0.y + zo0.y};
    float2 h1 = {a1.x + bi.x + zi1.x + zo1.x, a1.y + bi.y + zi1.y + zo1.y};

#pragma unroll
    for (int l = 0; l < 2; ++l) {
        float2 bov = *(const float2*)&bo_all[l * DD + d2];
        float2 gg  = *(const float2*)&g_all[l * DD + d2];
        float2 bb  = *(const float2*)&b_all[l * DD + d2];
        float2 bffv = *(const float2*)&bff_all[l * DD + d2];
        const float* Wl = Wff_all + (size_t)l * DD * DD;

        float2 xp0 = {h0.x + bov.x, h0.y + bov.y};
        float2 xp1 = {h1.x + bov.x, h1.y + bov.y};
        float mu0 = wsum(xp0.x + xp0.y) * (1.f / 128.f);
        float mu1 = wsum(xp1.x + xp1.y) * (1.f / 128.f);
        float c00 = xp0.x - mu0, c01 = xp0.y - mu0;
        float c10 = xp1.x - mu1, c11 = xp1.y - mu1;
        float r0 = rsqrtf(wsum(c00 * c00 + c01 * c01) * (1.f / 128.f) + 1e-5f);
        float r1 = rsqrtf(wsum(c10 * c10 + c11 * c11) * (1.f / 128.f) + 1e-5f);
        *(float2*)&y0[d2] = make_float2(c00 * r0 * gg.x + bb.x, c01 * r0 * gg.y + bb.y);
        *(float2*)&y1[d2] = make_float2(c10 * r1 * gg.x + bb.x, c11 * r1 * gg.y + bb.y);
        lds_fence();
        a0 = make_float2(0.f, 0.f); a1 = make_float2(0.f, 0.f);
        gemm2(Wl, y0, y1, 32, d2, a0, a1);          // FF GEMM, K=128
        h0 = make_float2(a0.x + bffv.x + xp0.x, a0.y + bffv.y + xp0.y);
        h1 = make_float2(a1.x + bffv.x + xp1.x, a1.y + bffv.y + xp1.y);
    }

    // out = h @ W_out + b_out
    *(float2*)&y0[d2] = h0;
    *(float2*)&y1[d2] = h1;
    lds_fence();
    a0 = make_float2(0.f, 0.f); a1 = make_float2(0.f, 0.f);
    gemm2(W_out, y0, y1, 32, d2, a0, a1);
    float2 bv = *(const float2*)&b_out[d2];
    *(float2*)&out[(size_t)n0 * DD + d2] = make_float2(a0.x + bv.x, a0.y + bv.y);
    *(float2*)&out[(size_t)(n0 + 1) * DD + d2] = make_float2(a1.x + bv.x, a1.y + bv.y);
}

extern "C" void kernel_launch(void* const* d_in, const int* in_sizes, int n_in,
                              void* d_out, int out_size, void* d_ws, size_t ws_size,
                              hipStream_t stream) {
    // inputs: 0 x, 1 edge_index, 2 ptr, 3 dist, 4 W_in, 5 b_in, 6 z_in, 7 z_out,
    // 8 b_spat, 9 Wq, 10 bq, 11 Wk, 12 bk, 13 Wv, 14 bv, 15 Wo, 16 bo,
    // 17 ln1_g, 18 ln1_b, 19 ln2_g, 20 ln2_b, 21 Wff, 22 bff, 23 W_out, 24 b_out
    const float* x = (const float*)d_in[0];
    const int* ei = (const int*)d_in[1];
    const float* W_in = (const float*)d_in[4];
    const float* b_in = (const float*)d_in[5];
    const float* z_in = (const float*)d_in[6];
    const float* z_out = (const float*)d_in[7];
    const float* bo = (const float*)d_in[16];
    const float* ln2_g = (const float*)d_in[19];
    const float* ln2_b = (const float*)d_in[20];
    const float* Wff = (const float*)d_in[21];
    const float* bff = (const float*)d_in[22];
    const float* W_out = (const float*)d_in[23];
    const float* b_out = (const float*)d_in[24];
    float* out = (float*)d_out;

    int* indeg = (int*)d_ws;
    int* outdeg = indeg + NN;

    k_zero<<<2 * NN / 256, 256, 0, stream>>>(indeg);
    k_deg<<<EE / (2 * 512), 512, 0, stream>>>(ei, indeg, outdeg);
    k_pipe<<<NN / 8, 256, 0, stream>>>(x, W_in, b_in, z_in, z_out, indeg, outdeg,
                                       bo, ln2_g, ln2_b, Wff, bff, W_out, b_out, out);
}

// Round 5
// 40.405 us; speedup vs baseline: 1.1818x; 1.1818x over previous
//
#include <hip/hip_runtime.h>

#define NN 4096
#define EE 65536
#define DD 128

// ---------------- zero degree arrays ----------------
__global__ void k_zero(int* __restrict__ p) {
    p[blockIdx.x * 256 + threadIdx.x] = 0;   // 32 x 256 = 8192 ints
}

// ---------------- degree count: 2 edges/thread via int2 ----------------
__global__ void k_deg(const int* __restrict__ ei, int* __restrict__ indeg,
                      int* __restrict__ outdeg) {
    int t = blockIdx.x * 512 + threadIdx.x;
    int2 s = *(const int2*)&ei[2 * t];
    int2 d = *(const int2*)&ei[EE + 2 * t];
    atomicAdd(&outdeg[s.x], 1);
    atomicAdd(&outdeg[s.y], 1);
    atomicAdd(&indeg[d.x], 1);
    atomicAdd(&indeg[d.y], 1);
}

// GEMM partial over a K-range: one W load (4B) feeds both nodes' FMAs.
__device__ __forceinline__ void gemm_part(const float* __restrict__ W, int ks,
                                          int nk4, int c,
                                          const float* __restrict__ y0,
                                          const float* __restrict__ y1,
                                          float& a0, float& a1) {
#pragma unroll 4
    for (int k4 = 0; k4 < nk4; ++k4) {
        float4 v0 = *(const float4*)&y0[ks + k4 * 4];   // LDS broadcast
        float4 v1 = *(const float4*)&y1[ks + k4 * 4];
#pragma unroll
        for (int kk = 0; kk < 4; ++kk) {
            float w = W[(size_t)(ks + k4 * 4 + kk) * DD + c];
            float e0 = kk == 0 ? v0.x : kk == 1 ? v0.y : kk == 2 ? v0.z : v0.w;
            float e1 = kk == 0 ? v1.x : kk == 1 ? v1.y : kk == 2 ? v1.z : v1.w;
            a0 += e0 * w;
            a1 += e1 * w;
        }
    }
}

// ---------------- fused h0 -> layer0 -> layer1 -> out ----------------
// block = 2 nodes; 256 thr = col c (0..127) x K-half kh (0..1). Full occupancy:
// 2048 blocks x 4 waves = 32 waves/CU. Attention output is exactly zero
// (multiplicative -1e6 mask -> softmax max is a huge positive cross-graph
// logit -> within-graph exp underflows to 0; the zero mask then kills the
// cross-graph cols), so only xp=h+bo and the LN2/FF path survive.
__global__ __launch_bounds__(256, 8) void k_all(
    const float* __restrict__ x, const float* __restrict__ W_in,
    const float* __restrict__ b_in, const float* __restrict__ z_in,
    const float* __restrict__ z_out, const int* __restrict__ indeg,
    const int* __restrict__ outdeg, const float* __restrict__ bo_all,
    const float* __restrict__ g_all, const float* __restrict__ b_all,
    const float* __restrict__ Wff_all, const float* __restrict__ bff_all,
    const float* __restrict__ W_out, const float* __restrict__ b_out,
    float* __restrict__ out) {
    __shared__ float ybuf[2][DD];   // activation rows for the 2 nodes
    __shared__ float part[2][DD];   // kh=1 partial sums
    __shared__ float xs[2][64];     // staged x rows
    __shared__ float red[2][2];     // LN cross-wave reduce [node][col-half]
    const int tid = threadIdx.x;
    const int c = tid & 127;        // output column
    const int kh = tid >> 7;        // K-half
    const int n0 = blockIdx.x * 2;

    // stage x rows (threads 0..127)
    if (tid < 128) xs[tid >> 6][tid & 63] = x[(size_t)(n0 + (tid >> 6)) * 64 + (tid & 63)];
    __syncthreads();

    // ---- h0 = x@W_in + b_in + z_in[indeg] + z_out[outdeg], K=64 ----
    float a0 = 0.f, a1 = 0.f;
    gemm_part(W_in, kh * 32, 8, c, xs[0], xs[1], a0, a1);
    if (kh) { part[0][c] = a0; part[1][c] = a1; }
    __syncthreads();
    float h0 = 0.f, h1 = 0.f;   // live only in kh==0 threads
    if (!kh) {
        int di0 = min(indeg[n0], 63), dq0 = min(outdeg[n0], 63);
        int di1 = min(indeg[n0 + 1], 63), dq1 = min(outdeg[n0 + 1], 63);
        float bi = b_in[c];
        h0 = a0 + part[0][c] + bi + z_in[(size_t)di0 * DD + c] + z_out[(size_t)dq0 * DD + c];
        h1 = a1 + part[1][c] + bi + z_in[(size_t)di1 * DD + c] + z_out[(size_t)dq1 * DD + c];
    }

    float xp0 = 0.f, xp1 = 0.f;
#pragma unroll
    for (int l = 0; l < 2; ++l) {
        // ---- LN(h + bo) -> ybuf (kh==0 threads; cols split across waves 0,1) ----
        if (!kh) {
            float bov = bo_all[l * DD + c];
            xp0 = h0 + bov;
            xp1 = h1 + bov;
            float s0 = xp0, s1 = xp1;
            for (int o = 32; o > 0; o >>= 1) {
                s0 += __shfl_xor(s0, o);
                s1 += __shfl_xor(s1, o);
            }
            if ((tid & 63) == 0) { red[0][tid >> 6] = s0; red[1][tid >> 6] = s1; }
        }
        __syncthreads();
        if (!kh) {
            float mu0 = (red[0][0] + red[0][1]) * (1.f / 128.f);
            float mu1 = (red[1][0] + red[1][1]) * (1.f / 128.f);
            float c0 = xp0 - mu0, c1 = xp1 - mu1;
            float v0 = c0 * c0, v1 = c1 * c1;
            for (int o = 32; o > 0; o >>= 1) {
                v0 += __shfl_xor(v0, o);
                v1 += __shfl_xor(v1, o);
            }
            if ((tid & 63) == 0) { red[0][tid >> 6] = v0; red[1][tid >> 6] = v1; }
            __syncthreads();   // NOTE: kh==1 threads hit the matching barrier below
            float r0 = rsqrtf((red[0][0] + red[0][1]) * (1.f / 128.f) + 1e-5f);
            float r1 = rsqrtf((red[1][0] + red[1][1]) * (1.f / 128.f) + 1e-5f);
            float gg = g_all[l * DD + c], bb = b_all[l * DD + c];
            ybuf[0][c] = c0 * r0 * gg + bb;
            ybuf[1][c] = c1 * r1 * gg + bb;
        } else {
            __syncthreads();   // matches the kh==0 inner barrier
        }
        __syncthreads();       // ybuf ready for both halves

        // ---- FF GEMM K=128 ----
        const float* Wl = Wff_all + (size_t)l * DD * DD;
        a0 = 0.f; a1 = 0.f;
        gemm_part(Wl, kh * 64, 16, c, ybuf[0], ybuf[1], a0, a1);
        if (kh) { part[0][c] = a0; part[1][c] = a1; }
        __syncthreads();
        if (!kh) {
            float bffv = bff_all[l * DD + c];
            h0 = a0 + part[0][c] + bffv + xp0;
            h1 = a1 + part[1][c] + bffv + xp1;
        }
    }

    // ---- out = h @ W_out + b_out ----
    if (!kh) { ybuf[0][c] = h0; ybuf[1][c] = h1; }
    __syncthreads();
    a0 = 0.f; a1 = 0.f;
    gemm_part(W_out, kh * 64, 16, c, ybuf[0], ybuf[1], a0, a1);
    if (kh) { part[0][c] = a0; part[1][c] = a1; }
    __syncthreads();
    if (!kh) {
        float bv = b_out[c];
        out[(size_t)n0 * DD + c] = a0 + part[0][c] + bv;
        out[(size_t)(n0 + 1) * DD + c] = a1 + part[1][c] + bv;
    }
}

extern "C" void kernel_launch(void* const* d_in, const int* in_sizes, int n_in,
                              void* d_out, int out_size, void* d_ws, size_t ws_size,
                              hipStream_t stream) {
    // inputs: 0 x, 1 edge_index, 2 ptr, 3 dist, 4 W_in, 5 b_in, 6 z_in, 7 z_out,
    // 8 b_spat, 9 Wq, 10 bq, 11 Wk, 12 bk, 13 Wv, 14 bv, 15 Wo, 16 bo,
    // 17 ln1_g, 18 ln1_b, 19 ln2_g, 20 ln2_b, 21 Wff, 22 bff, 23 W_out, 24 b_out
    const float* x = (const float*)d_in[0];
    const int* ei = (const int*)d_in[1];
    const float* W_in = (const float*)d_in[4];
    const float* b_in = (const float*)d_in[5];
    const float* z_in = (const float*)d_in[6];
    const float* z_out = (const float*)d_in[7];
    const float* bo = (const float*)d_in[16];
    const float* ln2_g = (const float*)d_in[19];
    const float* ln2_b = (const float*)d_in[20];
    const float* Wff = (const float*)d_in[21];
    const float* bff = (const float*)d_in[22];
    const float* W_out = (const float*)d_in[23];
    const float* b_out = (const float*)d_in[24];
    float* out = (float*)d_out;

    int* indeg = (int*)d_ws;
    int* outdeg = indeg + NN;

    k_zero<<<2 * NN / 256, 256, 0, stream>>>(indeg);
    k_deg<<<EE / (2 * 512), 512, 0, stream>>>(ei, indeg, outdeg);
    k_all<<<NN / 2, 256, 0, stream>>>(x, W_in, b_in, z_in, z_out, indeg, outdeg,
                                      bo, ln2_g, ln2_b, Wff, bff, W_out, b_out, out);
}

// Round 7
// 26.140 us; speedup vs baseline: 1.8268x; 1.5457x over previous
//
#include <hip/hip_runtime.h>

#define NN 4096
#define EE 65536
#define DD 128

// acc[i] += y[ng*8+i] @ W over this thread's K-quarter; one W dword -> 8 FMAs.
__device__ __forceinline__ void gemmq(const float* __restrict__ W, int kstart,
                                      int nk4, int c, const float* __restrict__ y,
                                      int ystr, float acc[8]) {
#pragma unroll 2
    for (int k4 = 0; k4 < nk4; ++k4) {
        int k = kstart + k4 * 4;
        float4 yv[8];
#pragma unroll
        for (int i = 0; i < 8; ++i)
            yv[i] = *(const float4*)&y[i * ystr + k];   // LDS broadcast (uniform addr)
#pragma unroll
        for (int kk = 0; kk < 4; ++kk) {
            float w = W[(size_t)(k + kk) * DD + c];     // L1, 8-way reuse across r
#pragma unroll
            for (int i = 0; i < 8; ++i) {
                float e = kk == 0 ? yv[i].x : kk == 1 ? yv[i].y
                        : kk == 2 ? yv[i].z : yv[i].w;
                acc[i] += e * w;
            }
        }
    }
}

// Single kernel: in-block degree scan + fused h0 -> layer0 -> layer1 -> out.
// Attention output is exactly zero (multiplicative -1e6 mask => softmax max is a
// huge positive cross-graph logit => within-graph exp underflows to 0; the zero
// mask then kills the cross-graph cols), so only xp=h+bo and the LN2/FF path survive.
// 256 blocks x 1024 thr; thread = (c=tid&127, ng=(tid>>7)&1 [8 nodes], ks=tid>>8 [K/4]).
__global__ __launch_bounds__(1024) void k_one(
    const float* __restrict__ x, const int* __restrict__ ei,
    const float* __restrict__ W_in, const float* __restrict__ b_in,
    const float* __restrict__ z_in, const float* __restrict__ z_out,
    const float* __restrict__ bo_all, const float* __restrict__ g_all,
    const float* __restrict__ b_all, const float* __restrict__ Wff_all,
    const float* __restrict__ bff_all, const float* __restrict__ W_out,
    const float* __restrict__ b_out, float* __restrict__ out) {
    __shared__ float part[4][16][DD];   // 32KB K-split partials
    __shared__ float hbuf[16][DD];      // 8KB  h / xp
    __shared__ float ybuf[16][DD];      // 8KB  LN output
    __shared__ float xs[16][64];        // 4KB  staged x rows
    __shared__ int cin[16], cout_[16];
    const int tid = threadIdx.x;
    const int n0 = blockIdx.x * 16;
    const int c = tid & 127;
    const int ng = (tid >> 7) & 1;
    const int ks = tid >> 8;            // 0..3

    // ---- stage x rows + zero degree counters ----
    xs[tid >> 6][tid & 63] = x[(size_t)(n0 + (tid >> 6)) * 64 + (tid & 63)];
    if (tid < 16) { cin[tid] = 0; cout_[tid] = 0; }
    __syncthreads();

    float acc[8];

    // ---- h0 GEMM (K=64, quarter=16) ----
#pragma unroll
    for (int i = 0; i < 8; ++i) acc[i] = 0.f;
    gemmq(W_in, ks * 16, 4, c, &xs[ng * 8][0], 64, acc);
#pragma unroll
    for (int i = 0; i < 8; ++i) part[ks][ng * 8 + i][c] = acc[i];

    // ---- degree scan: count this block's 16 nodes over all edges ----
    {
        const int4* s4 = (const int4*)ei;
        const int4* d4 = (const int4*)(ei + EE);
        for (int i = tid; i < EE / 4; i += 1024) {
            int4 s = s4[i];
            if ((unsigned)(s.x - n0) < 16u) atomicAdd(&cout_[s.x - n0], 1);
            if ((unsigned)(s.y - n0) < 16u) atomicAdd(&cout_[s.y - n0], 1);
            if ((unsigned)(s.z - n0) < 16u) atomicAdd(&cout_[s.z - n0], 1);
            if ((unsigned)(s.w - n0) < 16u) atomicAdd(&cout_[s.w - n0], 1);
            int4 d = d4[i];
            if ((unsigned)(d.x - n0) < 16u) atomicAdd(&cin[d.x - n0], 1);
            if ((unsigned)(d.y - n0) < 16u) atomicAdd(&cin[d.y - n0], 1);
            if ((unsigned)(d.z - n0) < 16u) atomicAdd(&cin[d.z - n0], 1);
            if ((unsigned)(d.w - n0) < 16u) atomicAdd(&cin[d.w - n0], 1);
        }
    }
    __syncthreads();

    // ---- h0 reduce + bias + centrality tables ----
#pragma unroll
    for (int p = 0; p < 2; ++p) {
        int idx = tid + p * 1024;
        int n = idx >> 7, cc = idx & 127;
        float v = part[0][n][cc] + part[1][n][cc] + part[2][n][cc] + part[3][n][cc];
        int di = min(cin[n], 63), dq = min(cout_[n], 63);
        hbuf[n][cc] = v + b_in[cc] + z_in[(size_t)di * DD + cc]
                        + z_out[(size_t)dq * DD + cc];
    }
    __syncthreads();

    // ---- 2 layers: xp = h + bo; h = LN(xp)@Wff + bff + xp ----
#pragma unroll
    for (int l = 0; l < 2; ++l) {
        // LN: wave-per-node, lane j handles cols j and j+64
        {
            int n = tid >> 6, j = tid & 63;
            float xpA = hbuf[n][j] + bo_all[l * DD + j];
            float xpB = hbuf[n][j + 64] + bo_all[l * DD + j + 64];
            float s = xpA + xpB;
            s += __shfl_xor(s, 32); s += __shfl_xor(s, 16); s += __shfl_xor(s, 8);
            s += __shfl_xor(s, 4);  s += __shfl_xor(s, 2);  s += __shfl_xor(s, 1);
            float mu = s * (1.f / 128.f);
            float cA = xpA - mu, cB = xpB - mu;
            float v = cA * cA + cB * cB;
            v += __shfl_xor(v, 32); v += __shfl_xor(v, 16); v += __shfl_xor(v, 8);
            v += __shfl_xor(v, 4);  v += __shfl_xor(v, 2);  v += __shfl_xor(v, 1);
            float rstd = rsqrtf(v * (1.f / 128.f) + 1e-5f);
            ybuf[n][j]      = cA * rstd * g_all[l * DD + j] + b_all[l * DD + j];
            ybuf[n][j + 64] = cB * rstd * g_all[l * DD + j + 64] + b_all[l * DD + j + 64];
            hbuf[n][j] = xpA;        // keep xp for residual (same-thread overwrite)
            hbuf[n][j + 64] = xpB;
        }
        __syncthreads();

        // FF GEMM (K=128, quarter=32)
        const float* Wl = Wff_all + l * DD * DD;
#pragma unroll
        for (int i = 0; i < 8; ++i) acc[i] = 0.f;
        gemmq(Wl, ks * 32, 8, c, &ybuf[ng * 8][0], DD, acc);
#pragma unroll
        for (int i = 0; i < 8; ++i) part[ks][ng * 8 + i][c] = acc[i];
        __syncthreads();

        // reduce + bff + residual
#pragma unroll
        for (int p = 0; p < 2; ++p) {
            int idx = tid + p * 1024;
            int n = idx >> 7, cc = idx & 127;
            float v = part[0][n][cc] + part[1][n][cc] + part[2][n][cc] + part[3][n][cc];
            hbuf[n][cc] = v + bff_all[l * DD + cc] + hbuf[n][cc];   // hbuf held xp
        }
        __syncthreads();
    }

    // ---- out = h @ W_out + b_out ----
#pragma unroll
    for (int i = 0; i < 8; ++i) acc[i] = 0.f;
    gemmq(W_out, ks * 32, 8, c, &hbuf[ng * 8][0], DD, acc);
#pragma unroll
    for (int i = 0; i < 8; ++i) part[ks][ng * 8 + i][c] = acc[i];
    __syncthreads();
#pragma unroll
    for (int p = 0; p < 2; ++p) {
        int idx = tid + p * 1024;
        int n = idx >> 7, cc = idx & 127;
        float v = part[0][n][cc] + part[1][n][cc] + part[2][n][cc] + part[3][n][cc];
        out[(size_t)(n0 + n) * DD + cc] = v + b_out[cc];
    }
}

extern "C" void kernel_launch(void* const* d_in, const int* in_sizes, int n_in,
                              void* d_out, int out_size, void* d_ws, size_t ws_size,
                              hipStream_t stream) {
    // inputs: 0 x, 1 edge_index, 2 ptr, 3 dist, 4 W_in, 5 b_in, 6 z_in, 7 z_out,
    // 8 b_spat, 9 Wq, 10 bq, 11 Wk, 12 bk, 13 Wv, 14 bv, 15 Wo, 16 bo,
    // 17 ln1_g, 18 ln1_b, 19 ln2_g, 20 ln2_b, 21 Wff, 22 bff, 23 W_out, 24 b_out
    const float* x = (const float*)d_in[0];
    const int* ei = (const int*)d_in[1];
    const float* W_in = (const float*)d_in[4];
    const float* b_in = (const float*)d_in[5];
    const float* z_in = (const float*)d_in[6];
    const float* z_out = (const float*)d_in[7];
    const float* bo = (const float*)d_in[16];
    const float* ln2_g = (const float*)d_in[19];
    const float* ln2_b = (const float*)d_in[20];
    const float* Wff = (const float*)d_in[21];
    const float* bff = (const float*)d_in[22];
    const float* W_out = (const float*)d_in[23];
    const float* b_out = (const float*)d_in[24];
    float* out = (float*)d_out;

    k_one<<<NN / 16, 1024, 0, stream>>>(x, ei, W_in, b_in, z_in, z_out,
                                        bo, ln2_g, ln2_b, Wff, bff, W_out, b_out, out);
}